// Round 14
// baseline (328.897 us; speedup 1.0000x reference)
//
#include <hip/hip_runtime.h>
#include <hip/hip_bf16.h>

#define DEVINL __device__ __forceinline__

typedef __attribute__((ext_vector_type(4))) float f32x4;
typedef __attribute__((ext_vector_type(8))) short short8;
typedef __attribute__((ext_vector_type(4))) short short4v;

constexpr int CB = 2, CT = 2048, CD = 1024, CH = 16, CDK = 64;
constexpr int CM = CB * CT; // 4096 rows
constexpr float LOG2E = 1.44269504088896340736f;

DEVINL ushort f2bf(float f) {
  __hip_bfloat16 h = __float2bfloat16(f); // RNE
  ushort u; __builtin_memcpy(&u, &h, 2); return u;
}

DEVINL float bf2f(ushort u) {
  uint x = ((uint)u) << 16; float f; __builtin_memcpy(&f, &x, 4); return f;
}

DEVINL void gl2lds16(const ushort* g, ushort* ldsbase) {
  __builtin_amdgcn_global_load_lds(
      (const __attribute__((address_space(1))) void*)g,
      (__attribute__((address_space(3))) void*)ldsbase, 16, 0, 0);
}

// ------------- prep: f32->bf16 convert (6 tensors) + mask tile-flags, one launch -------------
__global__ void prep_kernel(const float* __restrict__ s0, ushort* __restrict__ d0, int n0,
                            const float* __restrict__ s1, ushort* __restrict__ d1, int n1,
                            const float* __restrict__ s2, ushort* __restrict__ d2, int n2,
                            const float* __restrict__ s3, ushort* __restrict__ d3, int n3,
                            const float* __restrict__ s4, ushort* __restrict__ d4, int n4,
                            const float* __restrict__ s5, ushort* __restrict__ d5, int n5,
                            const int* __restrict__ mask, uint* __restrict__ flags,
                            int cvt_blocks)
{
  if ((int)blockIdx.x >= cvt_blocks) {
    // ---- mask tile role: flags[b*1024+qb*32+kb] = all-nonzero over 64x64 tile ----
    const int tile = blockIdx.x - cvt_blocks;          // 2048 tiles
    const int b = tile >> 10, qb = (tile >> 5) & 31, kb = tile & 31;
    const int* base = mask + ((size_t)b * CT + qb * 64) * CT + kb * 64;
    const int r = threadIdx.x >> 2, c0 = (threadIdx.x & 3) * 16;
    int ok = 1;
    for (int j = 0; j < 4; ++j) {
      int4 v = *reinterpret_cast<const int4*>(base + (size_t)r * CT + c0 + j * 4);
      ok &= (v.x != 0) & (v.y != 0) & (v.z != 0) & (v.w != 0);
    }
    __shared__ int red[4];
    unsigned long long bal = __ballot(ok);
    if ((threadIdx.x & 63) == 0) red[threadIdx.x >> 6] = (bal == ~0ull);
    __syncthreads();
    if (threadIdx.x == 0) flags[tile] = (uint)(red[0] & red[1] & red[2] & red[3]);
    return;
  }
  int i = (blockIdx.x * blockDim.x + threadIdx.x) * 4;
  const float* s; ushort* d;
  if (i < n0) { s = s0; d = d0; }
  else if ((i -= n0) < n1) { s = s1; d = d1; }
  else if ((i -= n1) < n2) { s = s2; d = d2; }
  else if ((i -= n2) < n3) { s = s3; d = d3; }
  else if ((i -= n3) < n4) { s = s4; d = d4; }
  else if ((i -= n4) < n5) { s = s5; d = d5; }
  else return;
  float4 v = *reinterpret_cast<const float4*>(s + i);
  ushort4 o;
  o.x = f2bf(v.x); o.y = f2bf(v.y); o.z = f2bf(v.z); o.w = f2bf(v.w);
  *reinterpret_cast<ushort4*>(d + i) = o;
}

// ---------------- NT GEMM, 2-phase double-buffered global_load_lds (round-8) ----------------
__global__ __launch_bounds__(256, 2)
void gemm_nt_kernel(const ushort* __restrict__ A, const ushort* __restrict__ Bm,
                    const float* __restrict__ bias1, const float* __restrict__ bias2,
                    void* __restrict__ Out, void* __restrict__ Out2,
                    int M, int N, int K, int mode, float scale)
{
  constexpr int BM = 128, BN = 64, BK = 32;
  __shared__ __align__(16) ushort As[2][BM * BK];
  __shared__ __align__(16) ushort Bs[2][BN * BK];
  const int tid = threadIdx.x;
  const int lane = tid & 63, wid = tid >> 6;
  const int wr = wid >> 1, wc = wid & 1;
  const int bm0 = blockIdx.y * BM, bn0 = blockIdx.x * BN;
  const int rsel = lane & 15, ksel = (lane >> 4) * 8;
  const int srow = lane >> 2, sc8 = (lane & 3) * 8;

  f32x4 acc[4][2];
  for (int i = 0; i < 4; ++i) for (int j = 0; j < 2; ++j) acc[i][j] = f32x4{0.f, 0.f, 0.f, 0.f};

  auto stage = [&](int bu, int k0) {
    const int ra0 = wid * 32;
    gl2lds16(&A[(size_t)(bm0 + ra0 + srow) * K + k0 + sc8],      &As[bu][ra0 * BK]);
    gl2lds16(&A[(size_t)(bm0 + ra0 + 16 + srow) * K + k0 + sc8], &As[bu][(ra0 + 16) * BK]);
    const int rb0 = wid * 16;
    gl2lds16(&Bm[(size_t)(bn0 + rb0 + srow) * K + k0 + sc8],     &Bs[bu][rb0 * BK]);
  };

  stage(0, 0);
  __syncthreads();
  const int NKT = K / BK;
  int bu = 0;
  for (int kt = 0; kt < NKT; ++kt) {
    if (kt + 1 < NKT) stage(bu ^ 1, (kt + 1) * BK);
    short8 af[4], bfr[2];
    for (int mi = 0; mi < 4; ++mi)
      af[mi] = *reinterpret_cast<short8*>(&As[bu][(wr * 64 + mi * 16 + rsel) * BK + ksel]);
    for (int ni = 0; ni < 2; ++ni)
      bfr[ni] = *reinterpret_cast<short8*>(&Bs[bu][(wc * 32 + ni * 16 + rsel) * BK + ksel]);
    for (int mi = 0; mi < 4; ++mi)
      for (int ni = 0; ni < 2; ++ni)
        acc[mi][ni] = __builtin_amdgcn_mfma_f32_16x16x32_bf16(af[mi], bfr[ni], acc[mi][ni], 0, 0, 0);
    if (kt + 1 < NKT) { __syncthreads(); bu ^= 1; }
  }

  const int r0 = (lane >> 4) * 4;
  for (int mi = 0; mi < 4; ++mi)
    for (int ni = 0; ni < 2; ++ni) {
      int gj = bn0 + wc * 32 + ni * 16 + rsel;
      float bv = (mode == 3 && gj >= 1024) ? bias2[gj - 1024] : bias1[gj];
      for (int r = 0; r < 4; ++r) {
        int gi = bm0 + wr * 64 + mi * 16 + r0 + r;
        float v = (acc[mi][ni][r] + bv) * scale;
        if (mode == 2) {
          reinterpret_cast<float*>(Out)[(size_t)gi * N + gj] = v;
        } else {
          int bb = gi >> 11, t = gi & (CT - 1);
          if (mode == 3 && gj >= 1024) {
            int gjv = gj - 1024;
            reinterpret_cast<ushort*>(Out2)[(((size_t)(bb * CH + (gjv >> 6)) * CDK + (gjv & 63)) * CT + t)] = f2bf(v);
          } else {
            reinterpret_cast<ushort*>(Out)[(((size_t)(bb * CH + (gj >> 6)) * CT + t) * CDK + (gj & 63))] = f2bf(v);
          }
        }
      }
    }
}

// ------------- fused attention: swapped-QK, bf16 P-LDS, cached coalesced attn stores -------------
// grid: (T/128, B*H), 8 waves. Qb has 0.125*log2e folded in. Kb:(B,H,T,DK). Vt:(B,H,DK,T).
// A/B vs round 13: attn stores are plain cached f32x4 (L2-absorbed ack) instead of nontemporal.
__global__ __launch_bounds__(512, 6)
void attn_kernel(const ushort* __restrict__ Qb, const ushort* __restrict__ Kb,
                 const ushort* __restrict__ Vt, const int* __restrict__ mask,
                 const uint* __restrict__ flags,
                 float* __restrict__ attn_out, ushort* __restrict__ oh)
{
  __shared__ __align__(16) ushort Ks[2][64 * 64];
  __shared__ __align__(16) ushort Vs[2][64 * 64];
  __shared__ __align__(16) ushort Pf[8][16 * 64]; // per-wave 16x64 bf16, 16B-chunk XOR swizzle

  const int tid = threadIdx.x, wid = tid >> 6, lane = tid & 63;
  const int bh = blockIdx.y, b = bh >> 4, h = bh & 15;
  const int q0 = blockIdx.x * 128 + wid * 16;
  const int rsel = lane & 15, grp = lane >> 4, ksel = grp * 8;
  const int swz = rsel & 7;
  const uint* fl = flags + (b << 10) + ((q0 >> 6) << 5);
  const ushort* kpan = Kb + (size_t)bh * CT * CDK;
  const ushort* vpan = Vt + (size_t)bh * CDK * CT;

  // staging: 512 threads cover 64 rows x 8 col-chunks; source pre-swizzled (rule 21)
  const int strow = tid >> 3, stc = (tid & 7) ^ (strow & 7);

  auto stageK = [&](int bu, int k0) {
    gl2lds16(&kpan[(size_t)(k0 + strow) * CDK + stc * 8], &Ks[bu][(size_t)wid * 512]);
  };
  auto stageV = [&](int bu, int k0) {
    gl2lds16(&vpan[(size_t)strow * CT + k0 + stc * 8], &Vs[bu][(size_t)wid * 512]);
  };

  // Q fragments (B-operand): lane holds Q[q0+rsel][dk = grp*8..+8] halves
  short8 qa0, qa1;
  {
    const ushort* qrow = Qb + ((size_t)bh * CT + q0 + rsel) * CDK;
    qa0 = *reinterpret_cast<const short8*>(qrow + ksel);
    qa1 = *reinterpret_cast<const short8*>(qrow + 32 + ksel);
  }

  const int* mrow = mask + (size_t)b * CT * CT;
  const int qme = q0 + rsel; // this lane's q row (l-sum, mask)

  // ---- pass 1: l[q] = sum_k exp2(S) ; scalar per lane, dbuf K staging ----
  float l_lane = 0.f;
  stageK(0, 0);
  __syncthreads();
  int bu = 0;
  for (int kt = 0; kt < 32; ++kt) {
    const int k0 = kt * 64;
    if (kt + 1 < 32) stageK(bu ^ 1, k0 + 64);
    const uint f = fl[kt];
    for (int ni = 0; ni < 4; ++ni) {
      const int krow = ni * 16 + rsel;
      short8 kb0 = *reinterpret_cast<short8*>(&Ks[bu][krow * 64 + ((grp    ) ^ swz) * 8]);
      short8 kb1 = *reinterpret_cast<short8*>(&Ks[bu][krow * 64 + ((grp + 4) ^ swz) * 8]);
      f32x4 z = {0.f, 0.f, 0.f, 0.f};
      z = __builtin_amdgcn_mfma_f32_16x16x32_bf16(kb0, qa0, z, 0, 0, 0);
      z = __builtin_amdgcn_mfma_f32_16x16x32_bf16(kb1, qa1, z, 0, 0, 0);
      if (f) {
        l_lane += exp2f(z[0]) + exp2f(z[1]) + exp2f(z[2]) + exp2f(z[3]);
      } else {
        const int kb_ = k0 + ni * 16 + grp * 4;
        for (int r = 0; r < 4; ++r)
          l_lane += mrow[(size_t)qme * CT + kb_ + r] ? exp2f(z[r]) : 0.f;
      }
    }
    __syncthreads();
    bu ^= 1;
  }
  // reduce over the 4 grp-lanes sharing this rsel
  l_lane += __shfl_xor(l_lane, 16, 64);
  l_lane += __shfl_xor(l_lane, 32, 64);
  const float ll = __log2f(l_lane); // p_scaled = exp2(z - ll) == exp2(z)/l

  // ---- pass 2: recompute, P (prescaled bf16) -> LDS, cached attn store, PV; counted vmcnt ----
  f32x4 oacc[4];
  for (int nd = 0; nd < 4; ++nd) oacc[nd] = f32x4{0.f, 0.f, 0.f, 0.f};
  float* apan = attn_out + (size_t)bh * CT * CT;
  ushort* pw = &Pf[wid][0];

  stageK(0, 0);
  stageV(0, 0);
  asm volatile("s_waitcnt vmcnt(0)" ::: "memory");
  __builtin_amdgcn_s_barrier();
  asm volatile("" ::: "memory");
  bu = 0;
  for (int kt = 0; kt < 32; ++kt) {
    const int k0 = kt * 64;
    if (kt + 1 < 32) { stageK(bu ^ 1, k0 + 64); stageV(bu ^ 1, k0 + 64); }
    asm volatile("" ::: "memory"); // pin prefetch loads as the OLDEST vmem ops this iter
    const uint f = fl[kt];
    for (int ni = 0; ni < 4; ++ni) {
      const int krow = ni * 16 + rsel;
      short8 kb0 = *reinterpret_cast<short8*>(&Ks[bu][krow * 64 + ((grp    ) ^ swz) * 8]);
      short8 kb1 = *reinterpret_cast<short8*>(&Ks[bu][krow * 64 + ((grp + 4) ^ swz) * 8]);
      f32x4 z = {0.f, 0.f, 0.f, 0.f};
      z = __builtin_amdgcn_mfma_f32_16x16x32_bf16(kb0, qa0, z, 0, 0, 0);
      z = __builtin_amdgcn_mfma_f32_16x16x32_bf16(kb1, qa1, z, 0, 0, 0);
      float p0, p1, p2, p3;
      if (f) {
        p0 = exp2f(z[0] - ll); p1 = exp2f(z[1] - ll);
        p2 = exp2f(z[2] - ll); p3 = exp2f(z[3] - ll);
      } else {
        const size_t mb = (size_t)qme * CT + k0 + ni * 16 + grp * 4;
        p0 = mrow[mb + 0] ? exp2f(z[0] - ll) : 0.f;
        p1 = mrow[mb + 1] ? exp2f(z[1] - ll) : 0.f;
        p2 = mrow[mb + 2] ? exp2f(z[2] - ll) : 0.f;
        p3 = mrow[mb + 3] ? exp2f(z[3] - ll) : 0.f;
      }
      // lane's 4 elems at row rsel, elem off ni*16+grp*4 -> chunk 2ni+(grp>>1), half (grp&1)
      const int chpos = (2 * ni + (grp >> 1)) ^ swz;
      short4v pk = {(short)f2bf(p0), (short)f2bf(p1), (short)f2bf(p2), (short)f2bf(p3)};
      *reinterpret_cast<short4v*>(&pw[rsel * 64 + chpos * 8 + (grp & 1) * 4]) = pk;
    }
    // cooperative attn store: per row, 16 lanes x 4 elems = 256B contiguous, cached (L2 ack)
    for (int rr = 0; rr < 4; ++rr) {
      const int row = rr * 4 + grp;
      const int rs = row & 7;
      short4v pv4 = *reinterpret_cast<short4v*>(
          &pw[row * 64 + (((rsel >> 1) ^ rs)) * 8 + (rsel & 1) * 4]);
      f32x4 v = {bf2f((ushort)pv4[0]), bf2f((ushort)pv4[1]),
                 bf2f((ushort)pv4[2]), bf2f((ushort)pv4[3])};
      *reinterpret_cast<f32x4*>(apan + (size_t)(q0 + row) * CT + k0 + rsel * 4) = v;
    }
    // PV A-fragment: direct 16B reads (elems ksel..+8 -> chunk grp; 32+ksel -> chunk 4+grp)
    short8 pa0 = *reinterpret_cast<short8*>(&pw[rsel * 64 + ((grp    ) ^ swz) * 8]);
    short8 pa1 = *reinterpret_cast<short8*>(&pw[rsel * 64 + ((grp + 4) ^ swz) * 8]);
    for (int nd = 0; nd < 4; ++nd) {
      const int vrow = nd * 16 + rsel;
      short8 vb0 = *reinterpret_cast<short8*>(&Vs[bu][vrow * 64 + ((grp    ) ^ swz) * 8]);
      short8 vb1 = *reinterpret_cast<short8*>(&Vs[bu][vrow * 64 + ((grp + 4) ^ swz) * 8]);
      oacc[nd] = __builtin_amdgcn_mfma_f32_16x16x32_bf16(pa0, vb0, oacc[nd], 0, 0, 0);
      oacc[nd] = __builtin_amdgcn_mfma_f32_16x16x32_bf16(pa1, vb1, oacc[nd], 0, 0, 0);
    }
    // counted drain: wait only the 2 prefetch gl2lds (oldest); leave <=4 stores in flight
    asm volatile("s_waitcnt vmcnt(4)" ::: "memory");
    __builtin_amdgcn_s_barrier();
    asm volatile("" ::: "memory");
    bu ^= 1;
  }

  // oh write: P was pre-scaled, so oacc is already normalized
  for (int nd = 0; nd < 4; ++nd)
    for (int r = 0; r < 4; ++r) {
      int q = q0 + grp * 4 + r, d = nd * 16 + rsel;
      oh[((size_t)b * CT + q) * CD + h * CDK + d] = f2bf(oacc[nd][r]);
    }
}

// ---------------- launcher ----------------
extern "C" void kernel_launch(void* const* d_in, const int* in_sizes, int n_in,
                              void* d_out, int out_size, void* d_ws, size_t ws_size,
                              hipStream_t stream)
{
  const float* x_q  = (const float*)d_in[0];
  const float* x_kv = (const float*)d_in[1];
  const int*   mask = (const int*)d_in[2];
  const float* Wq = (const float*)d_in[3];
  const float* bq = (const float*)d_in[4];
  const float* Wk = (const float*)d_in[5];
  const float* bk = (const float*)d_in[6];
  const float* Wv = (const float*)d_in[7];
  const float* bv = (const float*)d_in[8];
  const float* Wo = (const float*)d_in[9];
  const float* bo = (const float*)d_in[10];

  float* out  = (float*)d_out;
  float* attn = out + (size_t)CB * CT * CD;

  char* w = (char*)d_ws;
  auto alloc = [&](size_t bytes) { char* p = w; w += (bytes + 255) & ~(size_t)255; return p; };
  ushort* xq_bf  = (ushort*)alloc((size_t)CM * CD * 2);
  ushort* xkv_bf = (ushort*)alloc((size_t)CM * CD * 2);
  ushort* Wq_bf  = (ushort*)alloc((size_t)CD * CD * 2);
  ushort* Wk_bf  = (ushort*)alloc((size_t)CD * CD * 2); // Wk_bf/Wv_bf contiguous (2MB each, 256-aligned)
  ushort* Wv_bf  = (ushort*)alloc((size_t)CD * CD * 2);
  ushort* Wo_bf  = (ushort*)alloc((size_t)CD * CD * 2);
  ushort* Q_bf   = (ushort*)alloc((size_t)CM * CD * 2);
  ushort* K_bf   = (ushort*)alloc((size_t)CM * CD * 2);
  ushort* Vt_bf  = (ushort*)alloc((size_t)CM * CD * 2);
  ushort* oh_bf  = (ushort*)alloc((size_t)CM * CD * 2);
  uint*   mflags = (uint*)alloc(2048 * sizeof(uint));

  {
    const int nx = CM * CD, nw = CD * CD;
    const int cvt_blocks = ((2 * nx + 4 * nw) / 4 + 255) / 256; // 12288
    hipLaunchKernelGGL(prep_kernel, dim3(cvt_blocks + 2048), dim3(256), 0, stream,
                       x_q, xq_bf, nx, x_kv, xkv_bf, nx,
                       Wq, Wq_bf, nw, Wk, Wk_bf, nw,
                       Wv, Wv_bf, nw, Wo, Wo_bf, nw,
                       mask, mflags, cvt_blocks);
  }

  hipLaunchKernelGGL(gemm_nt_kernel, dim3(CD / 64, CM / 128), dim3(256), 0, stream,
                     xq_bf, Wq_bf, bq, bq, (void*)Q_bf, nullptr, CM, CD, CD, 0, 0.125f * LOG2E);
  hipLaunchKernelGGL(gemm_nt_kernel, dim3(2 * CD / 64, CM / 128), dim3(256), 0, stream,
                     xkv_bf, Wk_bf, bk, bv, (void*)K_bf, (void*)Vt_bf, CM, 2 * CD, CD, 3, 1.0f);

  hipLaunchKernelGGL(attn_kernel, dim3(CT / 128, CB * CH), dim3(512), 0, stream,
                     Q_bf, K_bf, Vt_bf, mask, mflags, attn, oh_bf);

  hipLaunchKernelGGL(gemm_nt_kernel, dim3(CD / 64, CM / 128), dim3(256), 0, stream,
                     oh_bf, Wo_bf, bo, bo, d_out, nullptr, CM, CD, CD, 2, 1.0f);
}

// Round 15
// 293.952 us; speedup vs baseline: 1.1189x; 1.1189x over previous
//
#include <hip/hip_runtime.h>
#include <hip/hip_bf16.h>

#define DEVINL __device__ __forceinline__

typedef __attribute__((ext_vector_type(4))) float f32x4;
typedef __attribute__((ext_vector_type(8))) short short8;
typedef __attribute__((ext_vector_type(4))) short short4v;

constexpr int CB = 2, CT = 2048, CD = 1024, CH = 16, CDK = 64;
constexpr int CM = CB * CT; // 4096 rows
constexpr float LOG2E = 1.44269504088896340736f;

DEVINL ushort f2bf(float f) {
  __hip_bfloat16 h = __float2bfloat16(f); // RNE
  ushort u; __builtin_memcpy(&u, &h, 2); return u;
}

DEVINL float bf2f(ushort u) {
  uint x = ((uint)u) << 16; float f; __builtin_memcpy(&f, &x, 4); return f;
}

DEVINL void gl2lds16(const ushort* g, ushort* ldsbase) {
  __builtin_amdgcn_global_load_lds(
      (const __attribute__((address_space(1))) void*)g,
      (__attribute__((address_space(3))) void*)ldsbase, 16, 0, 0);
}

// ------------- prep: f32->bf16 convert (6 tensors) + mask tile-flags, one launch -------------
__global__ void prep_kernel(const float* __restrict__ s0, ushort* __restrict__ d0, int n0,
                            const float* __restrict__ s1, ushort* __restrict__ d1, int n1,
                            const float* __restrict__ s2, ushort* __restrict__ d2, int n2,
                            const float* __restrict__ s3, ushort* __restrict__ d3, int n3,
                            const float* __restrict__ s4, ushort* __restrict__ d4, int n4,
                            const float* __restrict__ s5, ushort* __restrict__ d5, int n5,
                            const int* __restrict__ mask, uint* __restrict__ flags,
                            int cvt_blocks)
{
  if ((int)blockIdx.x >= cvt_blocks) {
    const int tile = blockIdx.x - cvt_blocks;          // 2048 tiles
    const int b = tile >> 10, qb = (tile >> 5) & 31, kb = tile & 31;
    const int* base = mask + ((size_t)b * CT + qb * 64) * CT + kb * 64;
    const int r = threadIdx.x >> 2, c0 = (threadIdx.x & 3) * 16;
    int ok = 1;
    for (int j = 0; j < 4; ++j) {
      int4 v = *reinterpret_cast<const int4*>(base + (size_t)r * CT + c0 + j * 4);
      ok &= (v.x != 0) & (v.y != 0) & (v.z != 0) & (v.w != 0);
    }
    __shared__ int red[4];
    unsigned long long bal = __ballot(ok);
    if ((threadIdx.x & 63) == 0) red[threadIdx.x >> 6] = (bal == ~0ull);
    __syncthreads();
    if (threadIdx.x == 0) flags[tile] = (uint)(red[0] & red[1] & red[2] & red[3]);
    return;
  }
  int i = (blockIdx.x * blockDim.x + threadIdx.x) * 4;
  const float* s; ushort* d;
  if (i < n0) { s = s0; d = d0; }
  else if ((i -= n0) < n1) { s = s1; d = d1; }
  else if ((i -= n1) < n2) { s = s2; d = d2; }
  else if ((i -= n2) < n3) { s = s3; d = d3; }
  else if ((i -= n3) < n4) { s = s4; d = d4; }
  else if ((i -= n4) < n5) { s = s5; d = d5; }
  else return;
  float4 v = *reinterpret_cast<const float4*>(s + i);
  ushort4 o;
  o.x = f2bf(v.x); o.y = f2bf(v.y); o.z = f2bf(v.z); o.w = f2bf(v.w);
  *reinterpret_cast<ushort4*>(d + i) = o;
}

// -------- NT GEMM, m97 128x128 tile, single-barrier dbuf global_load_lds prefetch --------
// 4 waves (2x2), each wave owns 64x64 out (4x4 16x16x32 frags). BK=32.
// mode 0: bf16 -> (B,H,T,DK); mode 2: f32 row-major; mode 3: KV-merged (K | Vt).
__global__ __launch_bounds__(256, 2)
void gemm_nt_kernel(const ushort* __restrict__ A, const ushort* __restrict__ Bm,
                    const float* __restrict__ bias1, const float* __restrict__ bias2,
                    void* __restrict__ Out, void* __restrict__ Out2,
                    int M, int N, int K, int mode, float scale)
{
  constexpr int BM = 128, BN = 128, BK = 32;
  __shared__ __align__(16) ushort As[2][BM * BK];
  __shared__ __align__(16) ushort Bs[2][BN * BK];
  const int tid = threadIdx.x;
  const int lane = tid & 63, wid = tid >> 6;
  const int wr = wid >> 1, wc = wid & 1;
  const int bm0 = blockIdx.y * BM, bn0 = blockIdx.x * BN;
  const int rsel = lane & 15, grp = lane >> 4, ksel = grp * 8;
  const int gr = wid * 16 + (lane >> 2), gc8 = (lane & 3) * 8; // staging row 0..63, col chunk

  f32x4 acc[4][4];
  for (int i = 0; i < 4; ++i) for (int j = 0; j < 4; ++j) acc[i][j] = f32x4{0.f, 0.f, 0.f, 0.f};

  // per k-step: 4 gl2lds/thread; each wave covers 16 rows (64 lanes x 16B = 1KB) per call
  auto stage = [&](int bu, int k0) {
    gl2lds16(&A [(size_t)(bm0 + gr) * K + k0 + gc8],      &As[bu][wid * 512]);
    gl2lds16(&A [(size_t)(bm0 + 64 + gr) * K + k0 + gc8], &As[bu][2048 + wid * 512]);
    gl2lds16(&Bm[(size_t)(bn0 + gr) * K + k0 + gc8],      &Bs[bu][wid * 512]);
    gl2lds16(&Bm[(size_t)(bn0 + 64 + gr) * K + k0 + gc8], &Bs[bu][2048 + wid * 512]);
  };

  stage(0, 0);
  __syncthreads();
  const int NKT = K / BK;
  int bu = 0;
  for (int kt = 0; kt < NKT; ++kt) {
    if (kt + 1 < NKT) stage(bu ^ 1, (kt + 1) * BK); // prefetch overlaps compute
    short8 af[4], bfr[4];
    for (int mi = 0; mi < 4; ++mi)
      af[mi] = *reinterpret_cast<short8*>(&As[bu][(wr * 64 + mi * 16 + rsel) * BK + ksel]);
    for (int ni = 0; ni < 4; ++ni)
      bfr[ni] = *reinterpret_cast<short8*>(&Bs[bu][(wc * 64 + ni * 16 + rsel) * BK + ksel]);
    for (int mi = 0; mi < 4; ++mi)
      for (int ni = 0; ni < 4; ++ni)
        acc[mi][ni] = __builtin_amdgcn_mfma_f32_16x16x32_bf16(af[mi], bfr[ni], acc[mi][ni], 0, 0, 0);
    if (kt + 1 < NKT) { __syncthreads(); bu ^= 1; } // vmcnt(0)+barrier: staged tile ready
  }

  const int r0 = grp * 4;
  for (int mi = 0; mi < 4; ++mi)
    for (int ni = 0; ni < 4; ++ni) {
      int gj = bn0 + wc * 64 + ni * 16 + rsel;
      float bv = (mode == 3 && gj >= 1024) ? bias2[gj - 1024] : bias1[gj];
      for (int r = 0; r < 4; ++r) {
        int gi = bm0 + wr * 64 + mi * 16 + r0 + r;
        float v = (acc[mi][ni][r] + bv) * scale;
        if (mode == 2) {
          reinterpret_cast<float*>(Out)[(size_t)gi * N + gj] = v;
        } else {
          int bb = gi >> 11, t = gi & (CT - 1);
          if (mode == 3 && gj >= 1024) {
            int gjv = gj - 1024;
            reinterpret_cast<ushort*>(Out2)[(((size_t)(bb * CH + (gjv >> 6)) * CDK + (gjv & 63)) * CT + t)] = f2bf(v);
          } else {
            reinterpret_cast<ushort*>(Out)[(((size_t)(bb * CH + (gj >> 6)) * CT + t) * CDK + (gj & 63))] = f2bf(v);
          }
        }
      }
    }
}

// ------------- fused attention (round-13 exact): swapped-QK, bf16 P-LDS, NT stores -------------
__global__ __launch_bounds__(512, 6)
void attn_kernel(const ushort* __restrict__ Qb, const ushort* __restrict__ Kb,
                 const ushort* __restrict__ Vt, const int* __restrict__ mask,
                 const uint* __restrict__ flags,
                 float* __restrict__ attn_out, ushort* __restrict__ oh)
{
  __shared__ __align__(16) ushort Ks[2][64 * 64];
  __shared__ __align__(16) ushort Vs[2][64 * 64];
  __shared__ __align__(16) ushort Pf[8][16 * 64]; // per-wave 16x64 bf16, 16B-chunk XOR swizzle

  const int tid = threadIdx.x, wid = tid >> 6, lane = tid & 63;
  const int bh = blockIdx.y, b = bh >> 4, h = bh & 15;
  const int q0 = blockIdx.x * 128 + wid * 16;
  const int rsel = lane & 15, grp = lane >> 4, ksel = grp * 8;
  const int swz = rsel & 7;
  const uint* fl = flags + (b << 10) + ((q0 >> 6) << 5);
  const ushort* kpan = Kb + (size_t)bh * CT * CDK;
  const ushort* vpan = Vt + (size_t)bh * CDK * CT;

  const int strow = tid >> 3, stc = (tid & 7) ^ (strow & 7);

  auto stageK = [&](int bu, int k0) {
    gl2lds16(&kpan[(size_t)(k0 + strow) * CDK + stc * 8], &Ks[bu][(size_t)wid * 512]);
  };
  auto stageV = [&](int bu, int k0) {
    gl2lds16(&vpan[(size_t)strow * CT + k0 + stc * 8], &Vs[bu][(size_t)wid * 512]);
  };

  short8 qa0, qa1;
  {
    const ushort* qrow = Qb + ((size_t)bh * CT + q0 + rsel) * CDK;
    qa0 = *reinterpret_cast<const short8*>(qrow + ksel);
    qa1 = *reinterpret_cast<const short8*>(qrow + 32 + ksel);
  }

  const int* mrow = mask + (size_t)b * CT * CT;
  const int qme = q0 + rsel;

  // ---- pass 1: l[q] = sum_k exp2(S) ----
  float l_lane = 0.f;
  stageK(0, 0);
  __syncthreads();
  int bu = 0;
  for (int kt = 0; kt < 32; ++kt) {
    const int k0 = kt * 64;
    if (kt + 1 < 32) stageK(bu ^ 1, k0 + 64);
    const uint f = fl[kt];
    for (int ni = 0; ni < 4; ++ni) {
      const int krow = ni * 16 + rsel;
      short8 kb0 = *reinterpret_cast<short8*>(&Ks[bu][krow * 64 + ((grp    ) ^ swz) * 8]);
      short8 kb1 = *reinterpret_cast<short8*>(&Ks[bu][krow * 64 + ((grp + 4) ^ swz) * 8]);
      f32x4 z = {0.f, 0.f, 0.f, 0.f};
      z = __builtin_amdgcn_mfma_f32_16x16x32_bf16(kb0, qa0, z, 0, 0, 0);
      z = __builtin_amdgcn_mfma_f32_16x16x32_bf16(kb1, qa1, z, 0, 0, 0);
      if (f) {
        l_lane += exp2f(z[0]) + exp2f(z[1]) + exp2f(z[2]) + exp2f(z[3]);
      } else {
        const int kb_ = k0 + ni * 16 + grp * 4;
        for (int r = 0; r < 4; ++r)
          l_lane += mrow[(size_t)qme * CT + kb_ + r] ? exp2f(z[r]) : 0.f;
      }
    }
    __syncthreads();
    bu ^= 1;
  }
  l_lane += __shfl_xor(l_lane, 16, 64);
  l_lane += __shfl_xor(l_lane, 32, 64);
  const float ll = __log2f(l_lane); // p_scaled = exp2(z - ll) == exp2(z)/l

  // ---- pass 2: recompute, P (prescaled bf16) -> LDS, NT attn store, PV; counted vmcnt ----
  f32x4 oacc[4];
  for (int nd = 0; nd < 4; ++nd) oacc[nd] = f32x4{0.f, 0.f, 0.f, 0.f};
  float* apan = attn_out + (size_t)bh * CT * CT;
  ushort* pw = &Pf[wid][0];

  stageK(0, 0);
  stageV(0, 0);
  asm volatile("s_waitcnt vmcnt(0)" ::: "memory");
  __builtin_amdgcn_s_barrier();
  asm volatile("" ::: "memory");
  bu = 0;
  for (int kt = 0; kt < 32; ++kt) {
    const int k0 = kt * 64;
    if (kt + 1 < 32) { stageK(bu ^ 1, k0 + 64); stageV(bu ^ 1, k0 + 64); }
    asm volatile("" ::: "memory"); // pin prefetch loads as the OLDEST vmem ops this iter
    const uint f = fl[kt];
    for (int ni = 0; ni < 4; ++ni) {
      const int krow = ni * 16 + rsel;
      short8 kb0 = *reinterpret_cast<short8*>(&Ks[bu][krow * 64 + ((grp    ) ^ swz) * 8]);
      short8 kb1 = *reinterpret_cast<short8*>(&Ks[bu][krow * 64 + ((grp + 4) ^ swz) * 8]);
      f32x4 z = {0.f, 0.f, 0.f, 0.f};
      z = __builtin_amdgcn_mfma_f32_16x16x32_bf16(kb0, qa0, z, 0, 0, 0);
      z = __builtin_amdgcn_mfma_f32_16x16x32_bf16(kb1, qa1, z, 0, 0, 0);
      float p0, p1, p2, p3;
      if (f) {
        p0 = exp2f(z[0] - ll); p1 = exp2f(z[1] - ll);
        p2 = exp2f(z[2] - ll); p3 = exp2f(z[3] - ll);
      } else {
        const size_t mb = (size_t)qme * CT + k0 + ni * 16 + grp * 4;
        p0 = mrow[mb + 0] ? exp2f(z[0] - ll) : 0.f;
        p1 = mrow[mb + 1] ? exp2f(z[1] - ll) : 0.f;
        p2 = mrow[mb + 2] ? exp2f(z[2] - ll) : 0.f;
        p3 = mrow[mb + 3] ? exp2f(z[3] - ll) : 0.f;
      }
      const int chpos = (2 * ni + (grp >> 1)) ^ swz;
      short4v pk = {(short)f2bf(p0), (short)f2bf(p1), (short)f2bf(p2), (short)f2bf(p3)};
      *reinterpret_cast<short4v*>(&pw[rsel * 64 + chpos * 8 + (grp & 1) * 4]) = pk;
    }
    // cooperative attn store: per row, 16 lanes x 4 elems = 256B contiguous, NT
    for (int rr = 0; rr < 4; ++rr) {
      const int row = rr * 4 + grp;
      const int rs = row & 7;
      short4v pv4 = *reinterpret_cast<short4v*>(
          &pw[row * 64 + (((rsel >> 1) ^ rs)) * 8 + (rsel & 1) * 4]);
      f32x4 v = {bf2f((ushort)pv4[0]), bf2f((ushort)pv4[1]),
                 bf2f((ushort)pv4[2]), bf2f((ushort)pv4[3])};
      __builtin_nontemporal_store(v,
          reinterpret_cast<f32x4*>(apan + (size_t)(q0 + row) * CT + k0 + rsel * 4));
    }
    // PV A-fragment: direct 16B reads
    short8 pa0 = *reinterpret_cast<short8*>(&pw[rsel * 64 + ((grp    ) ^ swz) * 8]);
    short8 pa1 = *reinterpret_cast<short8*>(&pw[rsel * 64 + ((grp + 4) ^ swz) * 8]);
    for (int nd = 0; nd < 4; ++nd) {
      const int vrow = nd * 16 + rsel;
      short8 vb0 = *reinterpret_cast<short8*>(&Vs[bu][vrow * 64 + ((grp    ) ^ swz) * 8]);
      short8 vb1 = *reinterpret_cast<short8*>(&Vs[bu][vrow * 64 + ((grp + 4) ^ swz) * 8]);
      oacc[nd] = __builtin_amdgcn_mfma_f32_16x16x32_bf16(pa0, vb0, oacc[nd], 0, 0, 0);
      oacc[nd] = __builtin_amdgcn_mfma_f32_16x16x32_bf16(pa1, vb1, oacc[nd], 0, 0, 0);
    }
    // counted drain: wait only the 2 prefetch gl2lds (oldest); leave <=4 NT stores in flight
    asm volatile("s_waitcnt vmcnt(4)" ::: "memory");
    __builtin_amdgcn_s_barrier();
    asm volatile("" ::: "memory");
    bu ^= 1;
  }

  for (int nd = 0; nd < 4; ++nd)
    for (int r = 0; r < 4; ++r) {
      int q = q0 + grp * 4 + r, d = nd * 16 + rsel;
      oh[((size_t)b * CT + q) * CD + h * CDK + d] = f2bf(oacc[nd][r]);
    }
}

// ---------------- launcher ----------------
extern "C" void kernel_launch(void* const* d_in, const int* in_sizes, int n_in,
                              void* d_out, int out_size, void* d_ws, size_t ws_size,
                              hipStream_t stream)
{
  const float* x_q  = (const float*)d_in[0];
  const float* x_kv = (const float*)d_in[1];
  const int*   mask = (const int*)d_in[2];
  const float* Wq = (const float*)d_in[3];
  const float* bq = (const float*)d_in[4];
  const float* Wk = (const float*)d_in[5];
  const float* bk = (const float*)d_in[6];
  const float* Wv = (const float*)d_in[7];
  const float* bv = (const float*)d_in[8];
  const float* Wo = (const float*)d_in[9];
  const float* bo = (const float*)d_in[10];

  float* out  = (float*)d_out;
  float* attn = out + (size_t)CB * CT * CD;

  char* w = (char*)d_ws;
  auto alloc = [&](size_t bytes) { char* p = w; w += (bytes + 255) & ~(size_t)255; return p; };
  ushort* xq_bf  = (ushort*)alloc((size_t)CM * CD * 2);
  ushort* xkv_bf = (ushort*)alloc((size_t)CM * CD * 2);
  ushort* Wq_bf  = (ushort*)alloc((size_t)CD * CD * 2);
  ushort* Wk_bf  = (ushort*)alloc((size_t)CD * CD * 2); // Wk_bf/Wv_bf contiguous (2MB each, 256-aligned)
  ushort* Wv_bf  = (ushort*)alloc((size_t)CD * CD * 2);
  ushort* Wo_bf  = (ushort*)alloc((size_t)CD * CD * 2);
  ushort* Q_bf   = (ushort*)alloc((size_t)CM * CD * 2);
  ushort* K_bf   = (ushort*)alloc((size_t)CM * CD * 2);
  ushort* Vt_bf  = (ushort*)alloc((size_t)CM * CD * 2);
  ushort* oh_bf  = (ushort*)alloc((size_t)CM * CD * 2);
  uint*   mflags = (uint*)alloc(2048 * sizeof(uint));

  {
    const int nx = CM * CD, nw = CD * CD;
    const int cvt_blocks = ((2 * nx + 4 * nw) / 4 + 255) / 256; // 12288
    hipLaunchKernelGGL(prep_kernel, dim3(cvt_blocks + 2048), dim3(256), 0, stream,
                       x_q, xq_bf, nx, x_kv, xkv_bf, nx,
                       Wq, Wq_bf, nw, Wk, Wk_bf, nw,
                       Wv, Wv_bf, nw, Wo, Wo_bf, nw,
                       mask, mflags, cvt_blocks);
  }

  hipLaunchKernelGGL(gemm_nt_kernel, dim3(CD / 128, CM / 128), dim3(256), 0, stream,
                     xq_bf, Wq_bf, bq, bq, (void*)Q_bf, nullptr, CM, CD, CD, 0, 0.125f * LOG2E);
  hipLaunchKernelGGL(gemm_nt_kernel, dim3(2 * CD / 128, CM / 128), dim3(256), 0, stream,
                     xkv_bf, Wk_bf, bk, bv, (void*)K_bf, (void*)Vt_bf, CM, 2 * CD, CD, 3, 1.0f);

  hipLaunchKernelGGL(attn_kernel, dim3(CT / 128, CB * CH), dim3(512), 0, stream,
                     Q_bf, K_bf, Vt_bf, mask, mflags, attn, oh_bf);

  hipLaunchKernelGGL(gemm_nt_kernel, dim3(CD / 128, CM / 128), dim3(256), 0, stream,
                     oh_bf, Wo_bf, bo, bo, d_out, nullptr, CM, CD, CD, 2, 1.0f);
}

// Round 16
// 280.733 us; speedup vs baseline: 1.1716x; 1.0471x over previous
//
#include <hip/hip_runtime.h>
#include <hip/hip_bf16.h>

#define DEVINL __device__ __forceinline__

typedef __attribute__((ext_vector_type(4))) float f32x4;
typedef __attribute__((ext_vector_type(8))) short short8;
typedef __attribute__((ext_vector_type(4))) short short4v;

constexpr int CB = 2, CT = 2048, CD = 1024, CH = 16, CDK = 64;
constexpr int CM = CB * CT; // 4096 rows
constexpr float LOG2E = 1.44269504088896340736f;

DEVINL ushort f2bf(float f) {
  __hip_bfloat16 h = __float2bfloat16(f); // RNE
  ushort u; __builtin_memcpy(&u, &h, 2); return u;
}

DEVINL float bf2f(ushort u) {
  uint x = ((uint)u) << 16; float f; __builtin_memcpy(&f, &x, 4); return f;
}

DEVINL void gl2lds16(const ushort* g, ushort* ldsbase) {
  __builtin_amdgcn_global_load_lds(
      (const __attribute__((address_space(1))) void*)g,
      (__attribute__((address_space(3))) void*)ldsbase, 16, 0, 0);
}

// ------------- prep: f32->bf16 convert (6 tensors) + mask tile-flags, one launch -------------
__global__ void prep_kernel(const float* __restrict__ s0, ushort* __restrict__ d0, int n0,
                            const float* __restrict__ s1, ushort* __restrict__ d1, int n1,
                            const float* __restrict__ s2, ushort* __restrict__ d2, int n2,
                            const float* __restrict__ s3, ushort* __restrict__ d3, int n3,
                            const float* __restrict__ s4, ushort* __restrict__ d4, int n4,
                            const float* __restrict__ s5, ushort* __restrict__ d5, int n5,
                            const int* __restrict__ mask, uint* __restrict__ flags,
                            int cvt_blocks)
{
  if ((int)blockIdx.x >= cvt_blocks) {
    const int tile = blockIdx.x - cvt_blocks;          // 2048 tiles
    const int b = tile >> 10, qb = (tile >> 5) & 31, kb = tile & 31;
    const int* base = mask + ((size_t)b * CT + qb * 64) * CT + kb * 64;
    const int r = threadIdx.x >> 2, c0 = (threadIdx.x & 3) * 16;
    int ok = 1;
    for (int j = 0; j < 4; ++j) {
      int4 v = *reinterpret_cast<const int4*>(base + (size_t)r * CT + c0 + j * 4);
      ok &= (v.x != 0) & (v.y != 0) & (v.z != 0) & (v.w != 0);
    }
    __shared__ int red[4];
    unsigned long long bal = __ballot(ok);
    if ((threadIdx.x & 63) == 0) red[threadIdx.x >> 6] = (bal == ~0ull);
    __syncthreads();
    if (threadIdx.x == 0) flags[tile] = (uint)(red[0] & red[1] & red[2] & red[3]);
    return;
  }
  int i = (blockIdx.x * blockDim.x + threadIdx.x) * 4;
  const float* s; ushort* d;
  if (i < n0) { s = s0; d = d0; }
  else if ((i -= n0) < n1) { s = s1; d = d1; }
  else if ((i -= n1) < n2) { s = s2; d = d2; }
  else if ((i -= n2) < n3) { s = s3; d = d3; }
  else if ((i -= n3) < n4) { s = s4; d = d4; }
  else if ((i -= n4) < n5) { s = s5; d = d5; }
  else return;
  float4 v = *reinterpret_cast<const float4*>(s + i);
  ushort4 o;
  o.x = f2bf(v.x); o.y = f2bf(v.y); o.z = f2bf(v.z); o.w = f2bf(v.w);
  *reinterpret_cast<ushort4*>(d + i) = o;
}

// ---------------- NT GEMM, 2-phase double-buffered global_load_lds (round-13 exact) ----------------
__global__ __launch_bounds__(256, 2)
void gemm_nt_kernel(const ushort* __restrict__ A, const ushort* __restrict__ Bm,
                    const float* __restrict__ bias1, const float* __restrict__ bias2,
                    void* __restrict__ Out, void* __restrict__ Out2,
                    int M, int N, int K, int mode, float scale)
{
  constexpr int BM = 128, BN = 64, BK = 32;
  __shared__ __align__(16) ushort As[2][BM * BK];
  __shared__ __align__(16) ushort Bs[2][BN * BK];
  const int tid = threadIdx.x;
  const int lane = tid & 63, wid = tid >> 6;
  const int wr = wid >> 1, wc = wid & 1;
  const int bm0 = blockIdx.y * BM, bn0 = blockIdx.x * BN;
  const int rsel = lane & 15, ksel = (lane >> 4) * 8;
  const int srow = lane >> 2, sc8 = (lane & 3) * 8;

  f32x4 acc[4][2];
  for (int i = 0; i < 4; ++i) for (int j = 0; j < 2; ++j) acc[i][j] = f32x4{0.f, 0.f, 0.f, 0.f};

  auto stage = [&](int bu, int k0) {
    const int ra0 = wid * 32;
    gl2lds16(&A[(size_t)(bm0 + ra0 + srow) * K + k0 + sc8],      &As[bu][ra0 * BK]);
    gl2lds16(&A[(size_t)(bm0 + ra0 + 16 + srow) * K + k0 + sc8], &As[bu][(ra0 + 16) * BK]);
    const int rb0 = wid * 16;
    gl2lds16(&Bm[(size_t)(bn0 + rb0 + srow) * K + k0 + sc8],     &Bs[bu][rb0 * BK]);
  };

  stage(0, 0);
  __syncthreads();
  const int NKT = K / BK;
  int bu = 0;
  for (int kt = 0; kt < NKT; ++kt) {
    if (kt + 1 < NKT) stage(bu ^ 1, (kt + 1) * BK);
    short8 af[4], bfr[2];
    for (int mi = 0; mi < 4; ++mi)
      af[mi] = *reinterpret_cast<short8*>(&As[bu][(wr * 64 + mi * 16 + rsel) * BK + ksel]);
    for (int ni = 0; ni < 2; ++ni)
      bfr[ni] = *reinterpret_cast<short8*>(&Bs[bu][(wc * 32 + ni * 16 + rsel) * BK + ksel]);
    for (int mi = 0; mi < 4; ++mi)
      for (int ni = 0; ni < 2; ++ni)
        acc[mi][ni] = __builtin_amdgcn_mfma_f32_16x16x32_bf16(af[mi], bfr[ni], acc[mi][ni], 0, 0, 0);
    if (kt + 1 < NKT) { __syncthreads(); bu ^= 1; }
  }

  const int r0 = (lane >> 4) * 4;
  for (int mi = 0; mi < 4; ++mi)
    for (int ni = 0; ni < 2; ++ni) {
      int gj = bn0 + wc * 32 + ni * 16 + rsel;
      float bv = (mode == 3 && gj >= 1024) ? bias2[gj - 1024] : bias1[gj];
      for (int r = 0; r < 4; ++r) {
        int gi = bm0 + wr * 64 + mi * 16 + r0 + r;
        float v = (acc[mi][ni][r] + bv) * scale;
        if (mode == 2) {
          reinterpret_cast<float*>(Out)[(size_t)gi * N + gj] = v;
        } else {
          int bb = gi >> 11, t = gi & (CT - 1);
          if (mode == 3 && gj >= 1024) {
            int gjv = gj - 1024;
            reinterpret_cast<ushort*>(Out2)[(((size_t)(bb * CH + (gjv >> 6)) * CDK + (gjv & 63)) * CT + t)] = f2bf(v);
          } else {
            reinterpret_cast<ushort*>(Out)[(((size_t)(bb * CH + (gj >> 6)) * CT + t) * CDK + (gj & 63))] = f2bf(v);
          }
        }
      }
    }
}

// ---- fused attention, 2 supertiles/block with phase overlap: P2(A) fused with P1(B) ----
// grid: (T/256, B*H), 8 waves, 256 q-rows per block (A: q0..+128, B: +128..+256).
// Phase1: lsum(A). Phase2: per K-tile, QK(B)->lsum(B) rides inside pass2(A)'s write window
// (shared Ks fragments). Phase3: pass2(B). NT coalesced attn stores, counted vmcnt.
__global__ __launch_bounds__(512, 2)
void attn_kernel(const ushort* __restrict__ Qb, const ushort* __restrict__ Kb,
                 const ushort* __restrict__ Vt, const int* __restrict__ mask,
                 const uint* __restrict__ flags,
                 float* __restrict__ attn_out, ushort* __restrict__ oh)
{
  __shared__ __align__(16) ushort Ks[2][64 * 64];
  __shared__ __align__(16) ushort Vs[2][64 * 64];
  __shared__ __align__(16) ushort Pf[8][16 * 64]; // per-wave 16x64 bf16, 16B-chunk XOR swizzle

  const int tid = threadIdx.x, wid = tid >> 6, lane = tid & 63;
  const int bh = blockIdx.y, b = bh >> 4, h = bh & 15;
  const int q0A = blockIdx.x * 256 + wid * 16;
  const int q0B = q0A + 128;
  const int rsel = lane & 15, grp = lane >> 4, ksel = grp * 8;
  const int swz = rsel & 7;
  const uint* flA = flags + (b << 10) + ((q0A >> 6) << 5);
  const uint* flB = flags + (b << 10) + ((q0B >> 6) << 5);
  const ushort* kpan = Kb + (size_t)bh * CT * CDK;
  const ushort* vpan = Vt + (size_t)bh * CDK * CT;

  const int strow = tid >> 3, stc = (tid & 7) ^ (strow & 7);

  auto stageK = [&](int bu, int k0) {
    gl2lds16(&kpan[(size_t)(k0 + strow) * CDK + stc * 8], &Ks[bu][(size_t)wid * 512]);
  };
  auto stageV = [&](int bu, int k0) {
    gl2lds16(&vpan[(size_t)strow * CT + k0 + stc * 8], &Vs[bu][(size_t)wid * 512]);
  };

  short8 qaA0, qaA1, qaB0, qaB1;
  {
    const ushort* qrowA = Qb + ((size_t)bh * CT + q0A + rsel) * CDK;
    qaA0 = *reinterpret_cast<const short8*>(qrowA + ksel);
    qaA1 = *reinterpret_cast<const short8*>(qrowA + 32 + ksel);
    const ushort* qrowB = Qb + ((size_t)bh * CT + q0B + rsel) * CDK;
    qaB0 = *reinterpret_cast<const short8*>(qrowB + ksel);
    qaB1 = *reinterpret_cast<const short8*>(qrowB + 32 + ksel);
  }

  const int* mrow = mask + (size_t)b * CT * CT;
  const int qmeA = q0A + rsel, qmeB = q0B + rsel;
  float* apan = attn_out + (size_t)bh * CT * CT;
  ushort* pw = &Pf[wid][0];

  // ---- phase 1: lsum(A) ----
  float lA = 0.f;
  stageK(0, 0);
  __syncthreads();
  int bu = 0;
  for (int kt = 0; kt < 32; ++kt) {
    const int k0 = kt * 64;
    if (kt + 1 < 32) stageK(bu ^ 1, k0 + 64);
    const uint f = flA[kt];
    for (int ni = 0; ni < 4; ++ni) {
      const int krow = ni * 16 + rsel;
      short8 kb0 = *reinterpret_cast<short8*>(&Ks[bu][krow * 64 + ((grp    ) ^ swz) * 8]);
      short8 kb1 = *reinterpret_cast<short8*>(&Ks[bu][krow * 64 + ((grp + 4) ^ swz) * 8]);
      f32x4 z = {0.f, 0.f, 0.f, 0.f};
      z = __builtin_amdgcn_mfma_f32_16x16x32_bf16(kb0, qaA0, z, 0, 0, 0);
      z = __builtin_amdgcn_mfma_f32_16x16x32_bf16(kb1, qaA1, z, 0, 0, 0);
      if (f) {
        lA += exp2f(z[0]) + exp2f(z[1]) + exp2f(z[2]) + exp2f(z[3]);
      } else {
        const int kb_ = k0 + ni * 16 + grp * 4;
        for (int r = 0; r < 4; ++r)
          lA += mrow[(size_t)qmeA * CT + kb_ + r] ? exp2f(z[r]) : 0.f;
      }
    }
    __syncthreads();
    bu ^= 1;
  }
  lA += __shfl_xor(lA, 16, 64);
  lA += __shfl_xor(lA, 32, 64);
  const float llA = __log2f(lA);

  // ---- phase 2: pass2(A) + lsum(B) fused (shared Ks fragments) ----
  f32x4 oacc[4];
  for (int nd = 0; nd < 4; ++nd) oacc[nd] = f32x4{0.f, 0.f, 0.f, 0.f};
  float lB = 0.f;

  stageK(0, 0);
  stageV(0, 0);
  asm volatile("s_waitcnt vmcnt(0)" ::: "memory");
  __builtin_amdgcn_s_barrier();
  asm volatile("" ::: "memory");
  bu = 0;
  for (int kt = 0; kt < 32; ++kt) {
    const int k0 = kt * 64;
    if (kt + 1 < 32) { stageK(bu ^ 1, k0 + 64); stageV(bu ^ 1, k0 + 64); }
    asm volatile("" ::: "memory"); // pin prefetch loads oldest
    const uint fA = flA[kt], fB = flB[kt];
    for (int ni = 0; ni < 4; ++ni) {
      const int krow = ni * 16 + rsel;
      short8 kb0 = *reinterpret_cast<short8*>(&Ks[bu][krow * 64 + ((grp    ) ^ swz) * 8]);
      short8 kb1 = *reinterpret_cast<short8*>(&Ks[bu][krow * 64 + ((grp + 4) ^ swz) * 8]);
      // --- B lsum (pure compute, fills A's write-bound window) ---
      {
        f32x4 z = {0.f, 0.f, 0.f, 0.f};
        z = __builtin_amdgcn_mfma_f32_16x16x32_bf16(kb0, qaB0, z, 0, 0, 0);
        z = __builtin_amdgcn_mfma_f32_16x16x32_bf16(kb1, qaB1, z, 0, 0, 0);
        if (fB) {
          lB += exp2f(z[0]) + exp2f(z[1]) + exp2f(z[2]) + exp2f(z[3]);
        } else {
          const int kb_ = k0 + ni * 16 + grp * 4;
          for (int r = 0; r < 4; ++r)
            lB += mrow[(size_t)qmeB * CT + kb_ + r] ? exp2f(z[r]) : 0.f;
        }
      }
      // --- A recompute -> P -> LDS ---
      f32x4 z = {0.f, 0.f, 0.f, 0.f};
      z = __builtin_amdgcn_mfma_f32_16x16x32_bf16(kb0, qaA0, z, 0, 0, 0);
      z = __builtin_amdgcn_mfma_f32_16x16x32_bf16(kb1, qaA1, z, 0, 0, 0);
      float p0, p1, p2, p3;
      if (fA) {
        p0 = exp2f(z[0] - llA); p1 = exp2f(z[1] - llA);
        p2 = exp2f(z[2] - llA); p3 = exp2f(z[3] - llA);
      } else {
        const size_t mb = (size_t)qmeA * CT + k0 + ni * 16 + grp * 4;
        p0 = mrow[mb + 0] ? exp2f(z[0] - llA) : 0.f;
        p1 = mrow[mb + 1] ? exp2f(z[1] - llA) : 0.f;
        p2 = mrow[mb + 2] ? exp2f(z[2] - llA) : 0.f;
        p3 = mrow[mb + 3] ? exp2f(z[3] - llA) : 0.f;
      }
      const int chpos = (2 * ni + (grp >> 1)) ^ swz;
      short4v pk = {(short)f2bf(p0), (short)f2bf(p1), (short)f2bf(p2), (short)f2bf(p3)};
      *reinterpret_cast<short4v*>(&pw[rsel * 64 + chpos * 8 + (grp & 1) * 4]) = pk;
    }
    // coalesced NT attn(A) store: 256B contiguous per row
    for (int rr = 0; rr < 4; ++rr) {
      const int row = rr * 4 + grp;
      const int rs = row & 7;
      short4v pv4 = *reinterpret_cast<short4v*>(
          &pw[row * 64 + (((rsel >> 1) ^ rs)) * 8 + (rsel & 1) * 4]);
      f32x4 v = {bf2f((ushort)pv4[0]), bf2f((ushort)pv4[1]),
                 bf2f((ushort)pv4[2]), bf2f((ushort)pv4[3])};
      __builtin_nontemporal_store(v,
          reinterpret_cast<f32x4*>(apan + (size_t)(q0A + row) * CT + k0 + rsel * 4));
    }
    // PV(A)
    short8 pa0 = *reinterpret_cast<short8*>(&pw[rsel * 64 + ((grp    ) ^ swz) * 8]);
    short8 pa1 = *reinterpret_cast<short8*>(&pw[rsel * 64 + ((grp + 4) ^ swz) * 8]);
    for (int nd = 0; nd < 4; ++nd) {
      const int vrow = nd * 16 + rsel;
      short8 vb0 = *reinterpret_cast<short8*>(&Vs[bu][vrow * 64 + ((grp    ) ^ swz) * 8]);
      short8 vb1 = *reinterpret_cast<short8*>(&Vs[bu][vrow * 64 + ((grp + 4) ^ swz) * 8]);
      oacc[nd] = __builtin_amdgcn_mfma_f32_16x16x32_bf16(pa0, vb0, oacc[nd], 0, 0, 0);
      oacc[nd] = __builtin_amdgcn_mfma_f32_16x16x32_bf16(pa1, vb1, oacc[nd], 0, 0, 0);
    }
    asm volatile("s_waitcnt vmcnt(4)" ::: "memory");
    __builtin_amdgcn_s_barrier();
    asm volatile("" ::: "memory");
    bu ^= 1;
  }
  // oh(A) write + B reduce
  for (int nd = 0; nd < 4; ++nd)
    for (int r = 0; r < 4; ++r) {
      int q = q0A + grp * 4 + r, d = nd * 16 + rsel;
      oh[((size_t)b * CT + q) * CD + h * CDK + d] = f2bf(oacc[nd][r]);
    }
  lB += __shfl_xor(lB, 16, 64);
  lB += __shfl_xor(lB, 32, 64);
  const float llB = __log2f(lB);

  // ---- phase 3: pass2(B) ----
  for (int nd = 0; nd < 4; ++nd) oacc[nd] = f32x4{0.f, 0.f, 0.f, 0.f};
  stageK(0, 0);
  stageV(0, 0);
  asm volatile("s_waitcnt vmcnt(0)" ::: "memory");
  __builtin_amdgcn_s_barrier();
  asm volatile("" ::: "memory");
  bu = 0;
  for (int kt = 0; kt < 32; ++kt) {
    const int k0 = kt * 64;
    if (kt + 1 < 32) { stageK(bu ^ 1, k0 + 64); stageV(bu ^ 1, k0 + 64); }
    asm volatile("" ::: "memory");
    const uint f = flB[kt];
    for (int ni = 0; ni < 4; ++ni) {
      const int krow = ni * 16 + rsel;
      short8 kb0 = *reinterpret_cast<short8*>(&Ks[bu][krow * 64 + ((grp    ) ^ swz) * 8]);
      short8 kb1 = *reinterpret_cast<short8*>(&Ks[bu][krow * 64 + ((grp + 4) ^ swz) * 8]);
      f32x4 z = {0.f, 0.f, 0.f, 0.f};
      z = __builtin_amdgcn_mfma_f32_16x16x32_bf16(kb0, qaB0, z, 0, 0, 0);
      z = __builtin_amdgcn_mfma_f32_16x16x32_bf16(kb1, qaB1, z, 0, 0, 0);
      float p0, p1, p2, p3;
      if (f) {
        p0 = exp2f(z[0] - llB); p1 = exp2f(z[1] - llB);
        p2 = exp2f(z[2] - llB); p3 = exp2f(z[3] - llB);
      } else {
        const size_t mb = (size_t)qmeB * CT + k0 + ni * 16 + grp * 4;
        p0 = mrow[mb + 0] ? exp2f(z[0] - llB) : 0.f;
        p1 = mrow[mb + 1] ? exp2f(z[1] - llB) : 0.f;
        p2 = mrow[mb + 2] ? exp2f(z[2] - llB) : 0.f;
        p3 = mrow[mb + 3] ? exp2f(z[3] - llB) : 0.f;
      }
      const int chpos = (2 * ni + (grp >> 1)) ^ swz;
      short4v pk = {(short)f2bf(p0), (short)f2bf(p1), (short)f2bf(p2), (short)f2bf(p3)};
      *reinterpret_cast<short4v*>(&pw[rsel * 64 + chpos * 8 + (grp & 1) * 4]) = pk;
    }
    for (int rr = 0; rr < 4; ++rr) {
      const int row = rr * 4 + grp;
      const int rs = row & 7;
      short4v pv4 = *reinterpret_cast<short4v*>(
          &pw[row * 64 + (((rsel >> 1) ^ rs)) * 8 + (rsel & 1) * 4]);
      f32x4 v = {bf2f((ushort)pv4[0]), bf2f((ushort)pv4[1]),
                 bf2f((ushort)pv4[2]), bf2f((ushort)pv4[3])};
      __builtin_nontemporal_store(v,
          reinterpret_cast<f32x4*>(apan + (size_t)(q0B + row) * CT + k0 + rsel * 4));
    }
    short8 pa0 = *reinterpret_cast<short8*>(&pw[rsel * 64 + ((grp    ) ^ swz) * 8]);
    short8 pa1 = *reinterpret_cast<short8*>(&pw[rsel * 64 + ((grp + 4) ^ swz) * 8]);
    for (int nd = 0; nd < 4; ++nd) {
      const int vrow = nd * 16 + rsel;
      short8 vb0 = *reinterpret_cast<short8*>(&Vs[bu][vrow * 64 + ((grp    ) ^ swz) * 8]);
      short8 vb1 = *reinterpret_cast<short8*>(&Vs[bu][vrow * 64 + ((grp + 4) ^ swz) * 8]);
      oacc[nd] = __builtin_amdgcn_mfma_f32_16x16x32_bf16(pa0, vb0, oacc[nd], 0, 0, 0);
      oacc[nd] = __builtin_amdgcn_mfma_f32_16x16x32_bf16(pa1, vb1, oacc[nd], 0, 0, 0);
    }
    asm volatile("s_waitcnt vmcnt(4)" ::: "memory");
    __builtin_amdgcn_s_barrier();
    asm volatile("" ::: "memory");
    bu ^= 1;
  }
  for (int nd = 0; nd < 4; ++nd)
    for (int r = 0; r < 4; ++r) {
      int q = q0B + grp * 4 + r, d = nd * 16 + rsel;
      oh[((size_t)b * CT + q) * CD + h * CDK + d] = f2bf(oacc[nd][r]);
    }
}

// ---------------- launcher ----------------
extern "C" void kernel_launch(void* const* d_in, const int* in_sizes, int n_in,
                              void* d_out, int out_size, void* d_ws, size_t ws_size,
                              hipStream_t stream)
{
  const float* x_q  = (const float*)d_in[0];
  const float* x_kv = (const float*)d_in[1];
  const int*   mask = (const int*)d_in[2];
  const float* Wq = (const float*)d_in[3];
  const float* bq = (const float*)d_in[4];
  const float* Wk = (const float*)d_in[5];
  const float* bk = (const float*)d_in[6];
  const float* Wv = (const float*)d_in[7];
  const float* bv = (const float*)d_in[8];
  const float* Wo = (const float*)d_in[9];
  const float* bo = (const float*)d_in[10];

  float* out  = (float*)d_out;
  float* attn = out + (size_t)CB * CT * CD;

  char* w = (char*)d_ws;
  auto alloc = [&](size_t bytes) { char* p = w; w += (bytes + 255) & ~(size_t)255; return p; };
  ushort* xq_bf  = (ushort*)alloc((size_t)CM * CD * 2);
  ushort* xkv_bf = (ushort*)alloc((size_t)CM * CD * 2);
  ushort* Wq_bf  = (ushort*)alloc((size_t)CD * CD * 2);
  ushort* Wk_bf  = (ushort*)alloc((size_t)CD * CD * 2); // Wk_bf/Wv_bf contiguous (2MB each, 256-aligned)
  ushort* Wv_bf  = (ushort*)alloc((size_t)CD * CD * 2);
  ushort* Wo_bf  = (ushort*)alloc((size_t)CD * CD * 2);
  ushort* Q_bf   = (ushort*)alloc((size_t)CM * CD * 2);
  ushort* K_bf   = (ushort*)alloc((size_t)CM * CD * 2);
  ushort* Vt_bf  = (ushort*)alloc((size_t)CM * CD * 2);
  ushort* oh_bf  = (ushort*)alloc((size_t)CM * CD * 2);
  uint*   mflags = (uint*)alloc(2048 * sizeof(uint));

  {
    const int nx = CM * CD, nw = CD * CD;
    const int cvt_blocks = ((2 * nx + 4 * nw) / 4 + 255) / 256; // 12288
    hipLaunchKernelGGL(prep_kernel, dim3(cvt_blocks + 2048), dim3(256), 0, stream,
                       x_q, xq_bf, nx, x_kv, xkv_bf, nx,
                       Wq, Wq_bf, nw, Wk, Wk_bf, nw,
                       Wv, Wv_bf, nw, Wo, Wo_bf, nw,
                       mask, mflags, cvt_blocks);
  }

  hipLaunchKernelGGL(gemm_nt_kernel, dim3(CD / 64, CM / 128), dim3(256), 0, stream,
                     xq_bf, Wq_bf, bq, bq, (void*)Q_bf, nullptr, CM, CD, CD, 0, 0.125f * LOG2E);
  hipLaunchKernelGGL(gemm_nt_kernel, dim3(2 * CD / 64, CM / 128), dim3(256), 0, stream,
                     xkv_bf, Wk_bf, bk, bv, (void*)K_bf, (void*)Vt_bf, CM, 2 * CD, CD, 3, 1.0f);

  hipLaunchKernelGGL(attn_kernel, dim3(CT / 256, CB * CH), dim3(512), 0, stream,
                     Q_bf, K_bf, Vt_bf, mask, mflags, attn, oh_bf);

  hipLaunchKernelGGL(gemm_nt_kernel, dim3(CD / 64, CM / 128), dim3(256), 0, stream,
                     oh_bf, Wo_bf, bo, bo, d_out, nullptr, CM, CD, CD, 2, 1.0f);
}